// Round 15
// baseline (79.789 us; speedup 1.0000x reference)
//
#include <hip/hip_runtime.h>
#include <math.h>

#define D 128
#define P_MAX 32        // plane row capacity (per-dst); deg>32 -> listB path
#define OCAP 65536      // listB capacity (row overflow)
#define CAPA 16384      // listA capacity (bucket-cap overflow, ~always 0)
#define CHUNK 4096      // edges per chunk in rank role
#define BCAP 4608       // per-bucket pairs capacity (mean 4096, +8 sigma)
#define SXP 140         // sX LDS row stride (floats)

using bf16x8 = __attribute__((ext_vector_type(8))) short;
using f32x4  = __attribute__((ext_vector_type(4))) float;
using i32x4  = __attribute__((ext_vector_type(4))) int;

__device__ __forceinline__ float int_or_float(const void* p) {
    int iv = *(const int*)p;
    if (iv > -1000000 && iv < 1000000) return (float)iv;
    return __int_as_float(iv);
}

__device__ __forceinline__ unsigned bf16_rne(float f) {
    unsigned u = __float_as_uint(f);
    return (u + 0x7fffu + ((u >> 16) & 1u)) >> 16;
}
__device__ __forceinline__ unsigned pack_bf2(float a, float b) {
    return bf16_rne(a) | (bf16_rne(b) << 16);
}

// ============================ TIER-1 kernels =============================

// k_zero: zero bcur/cntA/cntB (one block).
__global__ void k_zero(int* __restrict__ p, int nw) {
    for (int i = threadIdx.x; i < nw; i += 256) p[i] = 0;
}

// k_prepA: three concurrent roles by blockIdx:
//   [0, NBR)        rank: LDS-sort 4096-edge chunk by bucket (dst>>8), write
//                   contiguous runs into bucketed pairs array (coalesced)
//   [NBR, NBR+NBQ)  quant: xs8 = u8(x / s0), s0[r] = rowmax/127
//   [NBR+NBQ, +8)   wmt: Wm = theta*W + (1-theta)*I; block 0 zeroes guards
__global__ __launch_bounds__(256) void k_prepA(
        const int* __restrict__ src, const int* __restrict__ dst,
        int* __restrict__ bcur, int2* __restrict__ pairs,
        int* __restrict__ cntA, int2* __restrict__ listA,
        const float4* __restrict__ x4,
        uint2* __restrict__ xs8, float* __restrict__ s0,
        float* __restrict__ sxs,
        const float* __restrict__ W, uint4* __restrict__ wmt,
        const float* __restrict__ lamda_p, const void* __restrict__ l_p,
        int E, int n, int NBUK, int NBR, int NBQ) {
    const int t = threadIdx.x;
    int bid = blockIdx.x;

    if (bid < NBR) {                    // ---- rank role ----
        __shared__ int2 stag[CHUNK];    // 32 KB
        __shared__ int hist[256], scn[256], lb[256], gb[256];
        hist[t] = 0;
        __syncthreads();
        int base = bid * CHUNK;
        int2 e[16];
        int bk[16], rk[16];
        #pragma unroll
        for (int i = 0; i < 16; ++i) {
            int idx = base + i * 256 + t;
            if (idx < E) {
                e[i].x = src[idx];
                e[i].y = dst[idx];
                bk[i] = e[i].y >> 8;
                rk[i] = atomicAdd(&hist[bk[i]], 1);
            } else {
                bk[i] = -1;
            }
        }
        __syncthreads();
        scn[t] = hist[t];
        __syncthreads();
        for (int k = 1; k < 256; k <<= 1) {
            int add = (t >= k) ? scn[t - k] : 0;
            __syncthreads();
            scn[t] += add;
            __syncthreads();
        }
        lb[t] = scn[t] - hist[t];
        if (t < NBUK && hist[t] > 0) gb[t] = atomicAdd(&bcur[t], hist[t]);
        else gb[t] = 0;
        __syncthreads();
        #pragma unroll
        for (int i = 0; i < 16; ++i)
            if (bk[i] >= 0) stag[lb[bk[i]] + rk[i]] = e[i];
        __syncthreads();
        int total = scn[255];
        for (int p = t; p < total; p += 256) {
            int2 pr = stag[p];
            int b = pr.y >> 8;
            int slot = gb[b] + (p - lb[b]);
            if (slot < BCAP) {
                pairs[(size_t)b * BCAP + slot] = pr;
            } else {
                int o = atomicAdd(cntA, 1);
                if (o < CAPA) listA[o] = pr;
            }
        }
        return;
    }
    bid -= NBR;

    if (bid < NBQ) {                    // ---- quant role ----
        int gid = bid * 256 + t;
        int r = gid >> 4;
        if (r >= n) return;
        int q = gid & 15;
        float4 v0 = x4[(size_t)r * 32 + q * 2];
        float4 v1 = x4[(size_t)r * 32 + q * 2 + 1];
        float f[8] = {v0.x, v0.y, v0.z, v0.w, v1.x, v1.y, v1.z, v1.w};
        float m = 0.f;
        #pragma unroll
        for (int i = 0; i < 8; ++i) m = fmaxf(m, fabsf(f[i]));
        #pragma unroll
        for (int off = 1; off < 16; off <<= 1)
            m = fmaxf(m, __shfl_xor(m, off, 16));
        float s = m * (1.f / 127.f);
        float rs = m > 0.f ? 127.f / m : 0.f;
        unsigned b[8];
        #pragma unroll
        for (int i = 0; i < 8; ++i)
            b[i] = (unsigned)(__float2int_rn(f[i] * rs) + 128);
        uint2 o;
        o.x = b[0] | (b[1] << 8) | (b[2] << 16) | (b[3] << 24);
        o.y = b[4] | (b[5] << 8) | (b[6] << 16) | (b[7] << 24);
        xs8[(size_t)r * 16 + q] = o;
        if (q == 0) s0[r] = s;
        return;
    }
    bid -= NBQ;                         // ---- wmt role (bid 0..7) ----
    if (bid == 0) {                     // zero guards (row index -1)
        if (t < 32) ((unsigned*)xs8)[(int)t - 32] = 0u;
        if (t == 32) sxs[-1] = 0.f;
    }
    int tid = bid * 256 + t;
    float lamda = *lamda_p;
    float lf = int_or_float(l_p);
    float theta = logf(lamda / lf + 1.0f);
    float omt = 1.0f - theta;
    int ct = tid >> 8, kb = (tid >> 6) & 3, kg = (tid >> 4) & 3, lc = tid & 15;
    int c = ct * 16 + lc;
    int k0 = kb * 32 + kg * 8;
    float v[8];
    #pragma unroll
    for (int j = 0; j < 8; ++j) {
        float wv = theta * W[(size_t)(k0 + j) * D + c];
        if (k0 + j == c) wv += omt;
        v[j] = wv;
    }
    uint4 o;
    o.x = pack_bf2(v[0], v[1]);
    o.y = pack_bf2(v[2], v[3]);
    o.z = pack_bf2(v[4], v[5]);
    o.w = pack_bf2(v[6], v[7]);
    wmt[tid] = o;
}

// k_prepB: one block per bucket (256 dst rows). Build padded plane rows +
// deg in LDS, consume listA (bucket-cap overflow), emit listB (deg>32),
// write planes/deg/sxs coalesced.
__global__ __launch_bounds__(256) void k_prepB(
        const int2* __restrict__ pairs, const int* __restrict__ bcur,
        const int* __restrict__ cntA, const int2* __restrict__ listA,
        int* __restrict__ deg, int* __restrict__ planes,
        float* __restrict__ sxs, const float* __restrict__ s0,
        int* __restrict__ cntB, int2* __restrict__ listB, int n) {
    __shared__ int pl[256 * P_MAX];     // 32 KB
    __shared__ int dg[256];
    const int t = threadIdx.x;
    const int b = blockIdx.x;
    #pragma unroll
    for (int i = t; i < 256 * P_MAX; i += 256) pl[i] = -1;
    dg[t] = 0;
    __syncthreads();

    int count = bcur[b];
    if (count > BCAP) count = BCAP;
    const int2* bp = pairs + (size_t)b * BCAP;
    for (int i = t; i < count; i += 256) {
        int2 pr = bp[i];
        int lr = pr.y & 255;
        int rk = atomicAdd(&dg[lr], 1);
        if (rk < P_MAX) {
            pl[lr * P_MAX + rk] = pr.x;
        } else {
            int o = atomicAdd(cntB, 1);
            if (o < OCAP) listB[o] = pr;
        }
    }
    int ca = *cntA;                     // usually 0
    if (ca > CAPA) ca = CAPA;
    for (int i = t; i < ca; i += 256) {
        int2 pr = listA[i];
        if ((pr.y >> 8) == b) {
            int lr = pr.y & 255;
            int rk = atomicAdd(&dg[lr], 1);
            if (rk < P_MAX) {
                pl[lr * P_MAX + rk] = pr.x;
            } else {
                int o = atomicAdd(cntB, 1);
                if (o < OCAP) listB[o] = pr;
            }
        }
    }
    __syncthreads();

    int r0 = b * 256;
    for (int i = t; i < 256 * P_MAX; i += 256) {
        int r = r0 + (i >> 5);
        if (r < n) planes[(size_t)r * P_MAX + (i & 31)] = pl[i];
    }
    {
        int r = r0 + t;
        if (r < n) {
            int d = dg[t];
            deg[r] = d;
            int dd = d < 1 ? 1 : d;
            sxs[r] = s0[r] * rsqrtf((float)dd);
        }
    }
}

// dequant-accumulate 8 biased ubytes: a[i] += (float)byte_i * s
__device__ __forceinline__ void accq(float* a, uint2 v, float s) {
    a[0] += (float)(v.x & 0xffu) * s;
    a[1] += (float)((v.x >> 8) & 0xffu) * s;
    a[2] += (float)((v.x >> 16) & 0xffu) * s;
    a[3] += (float)(v.x >> 24) * s;
    a[4] += (float)(v.y & 0xffu) * s;
    a[5] += (float)((v.y >> 8) & 0xffu) * s;
    a[6] += (float)((v.y >> 16) & 0xffu) * s;
    a[7] += (float)(v.y >> 24) * s;
}

// k_fused: int8 gather (row-major planes, maskless, guard row -1) + support +
// MFMA GEMM + residual-from-xs8. Block = 256 threads = 4 waves, 16 rows.
// Streams (h0, planes, out) use nontemporal hints to preserve L2 for xs8.
__global__ __launch_bounds__(256) void k_fused(
        const uint2* __restrict__ xs8, const float* __restrict__ sxs,
        const float* __restrict__ s0, const int* __restrict__ planes,
        const int* __restrict__ deg, const int* __restrict__ cnt,
        const int2* __restrict__ opairs, const float* __restrict__ h0,
        const float* __restrict__ alpha_p, const uint4* __restrict__ wmt,
        float* __restrict__ out, int n) {
    __shared__ uint4 sS[256];           // 16 rows x 256 B support, swizzled
    __shared__ float sX[16 * SXP];      // 16 x 128 x-residual (stride 140)
    const int t = threadIdx.x;
    const int base = blockIdx.x * 16;

    {
        const int g = t >> 4;           // row group 0..15
        const int q = t & 15;
        int r = base + g;
        int rc = r < n ? r : 0;
        int d = r < n ? deg[rc] : 0;
        int dc = d < P_MAX ? d : P_MAX;
        const char* xsb = (const char*)xs8;
        const f32x4* h04 = (const f32x4*)h0;
        f32x4 hb0 = __builtin_nontemporal_load(&h04[(size_t)rc * 32 + q * 2]);
        f32x4 hb1 = __builtin_nontemporal_load(&h04[(size_t)rc * 32 + q * 2 + 1]);
        uint2 own = *(const uint2*)(xsb + (size_t)rc * 128 + q * 8);
        float s0r = s0[rc];
        const i32x4* prow = (const i32x4*)(planes + (size_t)rc * P_MAX);
        float a0[8] = {}, a1[8] = {}, a2[8] = {}, a3[8] = {};
        float ssum = 0.f;
        for (int p = 0; p < dc; p += 8) {
            i32x4 w0 = __builtin_nontemporal_load(&prow[(p >> 2) + 0]);
            i32x4 w1 = __builtin_nontemporal_load(&prow[(p >> 2) + 1]);
            float c0 = sxs[w0.x], c1 = sxs[w0.y], c2 = sxs[w0.z], c3 = sxs[w0.w];
            float c4 = sxs[w1.x], c5 = sxs[w1.y], c6 = sxs[w1.z], c7 = sxs[w1.w];
            uint2 v0 = *(const uint2*)(xsb + (long)w0.x * 128 + q * 8);
            uint2 v1 = *(const uint2*)(xsb + (long)w0.y * 128 + q * 8);
            uint2 v2 = *(const uint2*)(xsb + (long)w0.z * 128 + q * 8);
            uint2 v3 = *(const uint2*)(xsb + (long)w0.w * 128 + q * 8);
            uint2 v4 = *(const uint2*)(xsb + (long)w1.x * 128 + q * 8);
            uint2 v5 = *(const uint2*)(xsb + (long)w1.y * 128 + q * 8);
            uint2 v6 = *(const uint2*)(xsb + (long)w1.z * 128 + q * 8);
            uint2 v7 = *(const uint2*)(xsb + (long)w1.w * 128 + q * 8);
            accq(a0, v0, c0);
            accq(a1, v1, c1);
            accq(a2, v2, c2);
            accq(a3, v3, c3);
            accq(a0, v4, c4);
            accq(a1, v5, c5);
            accq(a2, v6, c6);
            accq(a3, v7, c7);
            ssum += ((c0 + c1) + (c2 + c3)) + ((c4 + c5) + (c6 + c7));
        }
        if (d > P_MAX) {                // rare (deg > 32): overflow edges
            int c = *cnt;
            if (c > OCAP) c = OCAP;
            for (int i = 0; i < c; ++i) {
                int2 pr = opairs[i];
                if (pr.y == r) {
                    float cs = sxs[pr.x];
                    uint2 v = *(const uint2*)(xsb + (long)pr.x * 128 + q * 8);
                    accq(a0, v, cs);
                    ssum += cs;
                }
            }
        }
        {
            float xi[8];
            xi[0] = ((float)(own.x & 0xffu) - 128.f) * s0r;
            xi[1] = ((float)((own.x >> 8) & 0xffu) - 128.f) * s0r;
            xi[2] = ((float)((own.x >> 16) & 0xffu) - 128.f) * s0r;
            xi[3] = ((float)(own.x >> 24) - 128.f) * s0r;
            xi[4] = ((float)(own.y & 0xffu) - 128.f) * s0r;
            xi[5] = ((float)((own.y >> 8) & 0xffu) - 128.f) * s0r;
            xi[6] = ((float)((own.y >> 16) & 0xffu) - 128.f) * s0r;
            xi[7] = ((float)(own.y >> 24) - 128.f) * s0r;
            *(float4*)&sX[g * SXP + q * 8] =
                make_float4(xi[0], xi[1], xi[2], xi[3]);
            *(float4*)&sX[g * SXP + q * 8 + 4] =
                make_float4(xi[4], xi[5], xi[6], xi[7]);
        }
        float di = rsqrtf((float)(d < 1 ? 1 : d));
        float alpha = *alpha_p;
        float ca = (1.0f - alpha) * di;
        float corr = 128.f * ssum;
        float t0 = ca * (((a0[0] + a1[0]) + (a2[0] + a3[0])) - corr) + alpha * hb0.x;
        float t1 = ca * (((a0[1] + a1[1]) + (a2[1] + a3[1])) - corr) + alpha * hb0.y;
        float t2 = ca * (((a0[2] + a1[2]) + (a2[2] + a3[2])) - corr) + alpha * hb0.z;
        float t3 = ca * (((a0[3] + a1[3]) + (a2[3] + a3[3])) - corr) + alpha * hb0.w;
        float t4 = ca * (((a0[4] + a1[4]) + (a2[4] + a3[4])) - corr) + alpha * hb1.x;
        float t5 = ca * (((a0[5] + a1[5]) + (a2[5] + a3[5])) - corr) + alpha * hb1.y;
        float t6 = ca * (((a0[6] + a1[6]) + (a2[6] + a3[6])) - corr) + alpha * hb1.z;
        float t7 = ca * (((a0[7] + a1[7]) + (a2[7] + a3[7])) - corr) + alpha * hb1.w;
        uint4 o;
        o.x = pack_bf2(t0, t1);
        o.y = pack_bf2(t2, t3);
        o.z = pack_bf2(t4, t5);
        o.w = pack_bf2(t6, t7);
        sS[g * 16 + (q ^ (g & 7))] = o;
    }
    __syncthreads();

    const int lane = t & 63;
    const int wv = t >> 6;              // wave 0..3
    const int lr = lane & 15;
    const int kg = lane >> 4;

    bf16x8 a[4];
    #pragma unroll
    for (int kb = 0; kb < 4; ++kb)
        a[kb] = ((const bf16x8*)sS)[lr * 16 + ((kb * 4 + kg) ^ (lr & 7))];

    const bf16x8* wfr = (const bf16x8*)wmt;
    #pragma unroll
    for (int j = 0; j < 2; ++j) {
        int ct = wv * 2 + j;
        f32x4 acc = (f32x4){0.f, 0.f, 0.f, 0.f};
        #pragma unroll
        for (int kb = 0; kb < 4; ++kb) {
            bf16x8 b = wfr[ct * 256 + kb * 64 + lane];
            acc = __builtin_amdgcn_mfma_f32_16x16x32_bf16(a[kb], b, acc, 0, 0, 0);
        }
        int c = ct * 16 + lr;
        #pragma unroll
        for (int reg = 0; reg < 4; ++reg) {
            int tr = kg * 4 + reg;
            int rr = base + tr;
            if (rr < n) {
                size_t off = (size_t)rr * D + c;
                __builtin_nontemporal_store(acc[reg] + sX[tr * SXP + c],
                                            &out[off]);
            }
        }
    }
}

// ==================== TIER-2 (old CSR path) kernels ======================

__global__ __launch_bounds__(256) void k_deg(const int* __restrict__ dst,
                                             int* __restrict__ deg, int E) {
    int i = blockIdx.x * 256 + threadIdx.x;
    if (i < E) atomicAdd(&deg[dst[i]], 1);
}

__global__ __launch_bounds__(256) void k_dinv(int* dd, int n) {
    int i = blockIdx.x * 256 + threadIdx.x;
    if (i < n) {
        int d = dd[i];
        if (d < 1) d = 1;
        ((float*)dd)[i] = rsqrtf((float)d);
    }
}

__global__ __launch_bounds__(256) void k_scan1(const int* __restrict__ deg,
                                               int* __restrict__ bsum, int n) {
    __shared__ int red[256];
    int b = blockIdx.x, t = threadIdx.x;
    int base = b * 1024;
    int s = 0;
    #pragma unroll
    for (int i = 0; i < 4; ++i) {
        int idx = base + i * 256 + t;
        if (idx < n) s += deg[idx];
    }
    red[t] = s;
    __syncthreads();
    for (int k = 128; k > 0; k >>= 1) {
        if (t < k) red[t] += red[t + k];
        __syncthreads();
    }
    if (t == 0) bsum[b] = red[0];
}

__global__ void k_scan2(const int* __restrict__ bsum, int* __restrict__ boff,
                        int* __restrict__ offsets, int nb, int n) {
    if (threadIdx.x == 0) {
        int acc = 0;
        for (int i = 0; i < nb; ++i) { boff[i] = acc; acc += bsum[i]; }
        offsets[n] = acc;
    }
}

__global__ __launch_bounds__(256) void k_scan3(int* __restrict__ deg,
                                               const int* __restrict__ boff,
                                               int* __restrict__ offsets,
                                               int* __restrict__ cursor, int n) {
    __shared__ int ls[256];
    int b = blockIdx.x, t = threadIdx.x;
    int base = b * 1024 + t * 4;
    int v[4];
    #pragma unroll
    for (int i = 0; i < 4; ++i) v[i] = (base + i < n) ? deg[base + i] : 0;
    int mysum = v[0] + v[1] + v[2] + v[3];
    ls[t] = mysum;
    __syncthreads();
    for (int k = 1; k < 256; k <<= 1) {
        int add = (t >= k) ? ls[t - k] : 0;
        __syncthreads();
        ls[t] += add;
        __syncthreads();
    }
    int p = boff[b] + ls[t] - mysum;
    #pragma unroll
    for (int i = 0; i < 4; ++i) {
        if (base + i < n) {
            offsets[base + i] = p;
            cursor[base + i] = p;
            int d = v[i] < 1 ? 1 : v[i];
            ((float*)deg)[base + i] = rsqrtf((float)d);
        }
        p += v[i];
    }
}

__global__ __launch_bounds__(256) void k_csr(const int* __restrict__ src,
                                             const int* __restrict__ dst,
                                             int* __restrict__ cursor,
                                             int* __restrict__ csr_src, int E) {
    int i = blockIdx.x * 256 + threadIdx.x;
    if (i < E) {
        int pos = atomicAdd(&cursor[dst[i]], 1);
        csr_src[pos] = src[i];
    }
}

__global__ __launch_bounds__(256) void k_gather(const float4* __restrict__ x4,
                                                const int* __restrict__ csr_src,
                                                const int* __restrict__ offsets,
                                                const float* __restrict__ dinv,
                                                float4* __restrict__ hacc, int n) {
    int idx = blockIdx.x * 256 + threadIdx.x;
    int r = idx >> 5;
    if (r >= n) return;
    int q = idx & 31;
    int e0 = offsets[r], e1 = offsets[r + 1];
    float4 a0 = make_float4(0.f, 0.f, 0.f, 0.f);
    float4 a1 = make_float4(0.f, 0.f, 0.f, 0.f);
    float4 a2 = make_float4(0.f, 0.f, 0.f, 0.f);
    float4 a3 = make_float4(0.f, 0.f, 0.f, 0.f);
    int e = e0;
    for (; e + 4 <= e1; e += 4) {
        int s0 = csr_src[e + 0];
        int s1 = csr_src[e + 1];
        int s2 = csr_src[e + 2];
        int s3 = csr_src[e + 3];
        float c0 = dinv[s0], c1 = dinv[s1], c2 = dinv[s2], c3 = dinv[s3];
        float4 v0 = x4[(size_t)s0 * (D / 4) + q];
        float4 v1 = x4[(size_t)s1 * (D / 4) + q];
        float4 v2 = x4[(size_t)s2 * (D / 4) + q];
        float4 v3 = x4[(size_t)s3 * (D / 4) + q];
        a0.x += v0.x * c0; a0.y += v0.y * c0; a0.z += v0.z * c0; a0.w += v0.w * c0;
        a1.x += v1.x * c1; a1.y += v1.y * c1; a1.z += v1.z * c1; a1.w += v1.w * c1;
        a2.x += v2.x * c2; a2.y += v2.y * c2; a2.z += v2.z * c2; a2.w += v2.w * c2;
        a3.x += v3.x * c3; a3.y += v3.y * c3; a3.z += v3.z * c3; a3.w += v3.w * c3;
    }
    for (; e < e1; ++e) {
        int s = csr_src[e];
        float c = dinv[s];
        float4 v = x4[(size_t)s * (D / 4) + q];
        a0.x += v.x * c; a0.y += v.y * c; a0.z += v.z * c; a0.w += v.w * c;
    }
    float4 acc;
    acc.x = (a0.x + a1.x) + (a2.x + a3.x);
    acc.y = (a0.y + a1.y) + (a2.y + a3.y);
    acc.z = (a0.z + a1.z) + (a2.z + a3.z);
    acc.w = (a0.w + a1.w) + (a2.w + a3.w);
    hacc[(size_t)r * (D / 4) + q] = acc;
}

__global__ __launch_bounds__(256) void k_scatter(const float4* __restrict__ x4,
                                                 const int* __restrict__ src,
                                                 const int* __restrict__ dst,
                                                 const float* __restrict__ dinv,
                                                 float* hacc, int E) {
    int idx = blockIdx.x * 256 + threadIdx.x;
    int e = idx >> 5;
    if (e >= E) return;
    int q = idx & 31;
    int s = src[e];
    int t = dst[e];
    float sc = dinv[s];
    float4 v = x4[(size_t)s * (D / 4) + q];
    float* h = hacc + (size_t)t * D + q * 4;
    unsafeAtomicAdd(h + 0, v.x * sc);
    unsafeAtomicAdd(h + 1, v.y * sc);
    unsafeAtomicAdd(h + 2, v.z * sc);
    unsafeAtomicAdd(h + 3, v.w * sc);
}

// old VALU epilogue (fallback paths)
__global__ __launch_bounds__(256) void k_final(float* io,
                                               const float* __restrict__ dinv,
                                               const float* __restrict__ h0,
                                               const float* __restrict__ x,
                                               const float* __restrict__ W,
                                               const float* __restrict__ lamda_p,
                                               const float* __restrict__ alpha_p,
                                               const void* __restrict__ l_p,
                                               int n) {
    __shared__ float sW[D * D];
    __shared__ float sSup[32][D];
    const int t = threadIdx.x;

    {
        const float4* W4 = (const float4*)W;
        float4* sW4 = (float4*)sW;
        #pragma unroll
        for (int i = 0; i < (D * D / 4) / 256; ++i)
            sW4[i * 256 + t] = W4[i * 256 + t];
    }

    const float alpha = *alpha_p;
    const float lamda = *lamda_p;
    const float lf = int_or_float(l_p);
    const float theta = logf(lamda / lf + 1.0f);
    const float omt = 1.0f - theta;
    const float oma = 1.0f - alpha;

    const int base = blockIdx.x * 32;

    {
        const float4* hacc4 = (const float4*)io;
        const float4* h04 = (const float4*)h0;
        #pragma unroll
        for (int i = 0; i < 4; ++i) {
            int v = i * 256 + t;
            int tr = v >> 5;
            int q = v & 31;
            int r = base + tr;
            float4 sup = make_float4(0.f, 0.f, 0.f, 0.f);
            if (r < n) {
                float ca = oma * dinv[r];
                float4 a = hacc4[(size_t)r * (D / 4) + q];
                float4 b = h04[(size_t)r * (D / 4) + q];
                sup.x = ca * a.x + alpha * b.x;
                sup.y = ca * a.y + alpha * b.y;
                sup.z = ca * a.z + alpha * b.z;
                sup.w = ca * a.w + alpha * b.w;
            }
            *(float4*)&sSup[tr][q * 4] = sup;
        }
    }
    __syncthreads();

    const int cg = t & 31;
    const int rb = t >> 5;
    float acc[4][4] = {};
    const float4* sW4 = (const float4*)sW;
    #pragma unroll 4
    for (int k = 0; k < D; ++k) {
        float4 w = sW4[k * 32 + cg];
        #pragma unroll
        for (int j = 0; j < 4; ++j) {
            float s = sSup[rb * 4 + j][k];
            acc[j][0] += s * w.x;
            acc[j][1] += s * w.y;
            acc[j][2] += s * w.z;
            acc[j][3] += s * w.w;
        }
    }

    #pragma unroll
    for (int j = 0; j < 4; ++j) {
        int tr = rb * 4 + j;
        int r = base + tr;
        if (r < n) {
            float4 xi = ((const float4*)x)[(size_t)r * (D / 4) + cg];
            float4 sp = *(const float4*)&sSup[tr][cg * 4];
            float4 o;
            o.x = theta * acc[j][0] + omt * sp.x + xi.x;
            o.y = theta * acc[j][1] + omt * sp.y + xi.y;
            o.z = theta * acc[j][2] + omt * sp.z + xi.z;
            o.w = theta * acc[j][3] + omt * sp.w + xi.w;
            ((float4*)io)[(size_t)r * (D / 4) + cg] = o;
        }
    }
}

// ================================ host ===================================

extern "C" void kernel_launch(void* const* d_in, const int* in_sizes, int n_in,
                              void* d_out, int out_size, void* d_ws, size_t ws_size,
                              hipStream_t stream) {
    const float* x = (const float*)d_in[0];
    const int* esrc = (const int*)d_in[1];
    const int* edst = (const int*)d_in[2];
    const float* h0 = (const float*)d_in[3];
    const float* W = (const float*)d_in[4];
    const float* lamda_p = (const float*)d_in[5];
    const float* alpha_p = (const float*)d_in[6];
    const void* l_p = d_in[7];

    const int E = in_sizes[1];
    const int n = in_sizes[0] / D;
    const int NBUK = (n + 255) >> 8;

    char* w = (char*)d_ws;

    // ---- tier-1 layout ----
    size_t o_bc  = 0;                                            // NBUK ints (bcur)
    size_t o_ca  = ((size_t)NBUK * 4 + 15) & ~15ull;             // cntA
    size_t o_cb  = o_ca + 16;                                    // cntB
    size_t o_la  = o_cb + 16;                                    // CAPA int2
    size_t o_lb  = (o_la + (size_t)CAPA * 8 + 15) & ~15ull;      // OCAP int2
    size_t o_deg = (o_lb + (size_t)OCAP * 8 + 15) & ~15ull;      // n ints
    size_t o_x8g = (o_deg + (size_t)n * 4 + 15) & ~15ull;        // 128B guard + n*128
    size_t o_sxg = (o_x8g + 128 + (size_t)n * 128 + 15) & ~15ull;// 16B guard + n floats
    size_t o_s0  = (o_sxg + 16 + (size_t)n * 4 + 15) & ~15ull;   // n floats
    size_t o_wmt = (o_s0 + (size_t)n * 4 + 15) & ~15ull;         // 32 KB
    size_t o_pl  = (o_wmt + 32768 + 15) & ~15ull;                // n*P_MAX ints
    size_t o_pr  = (o_pl + (size_t)n * P_MAX * 4 + 15) & ~15ull; // NBUK*BCAP int2
    size_t need1 = o_pr + (size_t)NBUK * BCAP * 8;

    if (ws_size >= need1 && NBUK <= 256) {
        int* bcur = (int*)(w + o_bc);
        int* cntA = (int*)(w + o_ca);
        int* cntB = (int*)(w + o_cb);
        int2* listA = (int2*)(w + o_la);
        int2* listB = (int2*)(w + o_lb);
        int* deg = (int*)(w + o_deg);
        uint2* xs8 = (uint2*)(w + o_x8g + 128);    // row -1 = zero guard
        float* sxs = (float*)(w + o_sxg + 16);     // sxs[-1] = zero guard
        float* s0 = (float*)(w + o_s0);
        uint4* wmt = (uint4*)(w + o_wmt);
        int* planes = (int*)(w + o_pl);
        int2* pairs = (int2*)(w + o_pr);

        k_zero<<<1, 256, 0, stream>>>((int*)w, (int)(o_la / 4));

        int NBR = (E + CHUNK - 1) / CHUNK;
        int NBQ = ((size_t)n * 16 + 255) / 256;
        k_prepA<<<NBR + NBQ + 8, 256, 0, stream>>>(
            esrc, edst, bcur, pairs, cntA, listA,
            (const float4*)x, xs8, s0, sxs, W, wmt, lamda_p, l_p,
            E, n, NBUK, NBR, NBQ);
        k_prepB<<<NBUK, 256, 0, stream>>>(
            pairs, bcur, cntA, listA, deg, planes, sxs, s0, cntB, listB, n);
        k_fused<<<(n + 15) / 16, 256, 0, stream>>>(
            xs8, sxs, s0, planes, deg, cntB, listB, h0, alpha_p, wmt,
            (float*)d_out, n);
        return;
    }

    // ---- tier-2: old CSR path ----
    const int nb = (n + 1023) / 1024;
    size_t t_deg = 0;
    size_t t_off = (t_deg + (size_t)n * 4 + 15) & ~15ull;
    size_t t_cur = (t_off + (size_t)(n + 1) * 4 + 15) & ~15ull;
    size_t t_bs  = (t_cur + (size_t)n * 4 + 15) & ~15ull;
    size_t t_bo  = (t_bs + (size_t)nb * 4 + 15) & ~15ull;
    size_t t_csr = (t_bo + (size_t)nb * 4 + 15) & ~15ull;
    size_t need2 = t_csr + (size_t)E * 4;

    int* deg = (int*)(w + t_deg);
    float* dinv = (float*)(w + t_deg);

    hipMemsetAsync(deg, 0, (size_t)n * sizeof(int), stream);
    k_deg<<<(E + 255) / 256, 256, 0, stream>>>(edst, deg, E);

    if (ws_size >= need2 && nb <= 1024) {
        int* offsets = (int*)(w + t_off);
        int* cursor  = (int*)(w + t_cur);
        int* bsum    = (int*)(w + t_bs);
        int* boff    = (int*)(w + t_bo);
        int* csr_src = (int*)(w + t_csr);

        k_scan1<<<nb, 256, 0, stream>>>(deg, bsum, n);
        k_scan2<<<1, 64, 0, stream>>>(bsum, boff, offsets, nb, n);
        k_scan3<<<nb, 256, 0, stream>>>(deg, boff, offsets, cursor, n);
        k_csr<<<(E + 255) / 256, 256, 0, stream>>>(esrc, edst, cursor, csr_src, E);
        k_gather<<<((size_t)n * 32 + 255) / 256, 256, 0, stream>>>(
            (const float4*)x, csr_src, offsets, dinv, (float4*)d_out, n);
    } else {
        k_dinv<<<(n + 255) / 256, 256, 0, stream>>>(deg, n);
        hipMemsetAsync(d_out, 0, (size_t)n * D * sizeof(float), stream);
        k_scatter<<<((size_t)E * 32 + 255) / 256, 256, 0, stream>>>(
            (const float4*)x, esrc, edst, dinv, (float*)d_out, E);
    }

    k_final<<<(n + 31) / 32, 256, 0, stream>>>(
        (float*)d_out, dinv, h0, x, W, lamda_p, alpha_p, l_p, n);
}

// Round 16
// 73.710 us; speedup vs baseline: 1.0825x; 1.0825x over previous
//
#include <hip/hip_runtime.h>
#include <math.h>

#define D 128
#define P_MAX 32        // plane row capacity (per-dst); deg>32 -> listB path
#define OCAP 65536      // listB capacity (row overflow)
#define CAPA 16384      // listA capacity (bucket-cap overflow, ~always 0)
#define CHUNK 2048      // edges per chunk in rank role
#define BCAP 4608       // per-bucket pairs capacity (mean 4096, +8 sigma)
#define SXP 140         // sX LDS row stride (floats)

using bf16x8 = __attribute__((ext_vector_type(8))) short;
using f32x4  = __attribute__((ext_vector_type(4))) float;

__device__ __forceinline__ float int_or_float(const void* p) {
    int iv = *(const int*)p;
    if (iv > -1000000 && iv < 1000000) return (float)iv;
    return __int_as_float(iv);
}

__device__ __forceinline__ unsigned bf16_rne(float f) {
    unsigned u = __float_as_uint(f);
    return (u + 0x7fffu + ((u >> 16) & 1u)) >> 16;
}
__device__ __forceinline__ unsigned pack_bf2(float a, float b) {
    return bf16_rne(a) | (bf16_rne(b) << 16);
}

// ============================ TIER-1 kernels =============================

// k_zero: zero bcur/cntA/cntB (one block).
__global__ void k_zero(int* __restrict__ p, int nw) {
    for (int i = threadIdx.x; i < nw; i += 256) p[i] = 0;
}

// k_prepA: three concurrent roles by blockIdx:
//   [0, NBR)        rank: LDS-sort 2048-edge chunk by bucket (dst>>8), write
//                   contiguous runs into bucketed pairs array (coalesced)
//   [NBR, NBR+NBQ)  quant: xs8 = u8(x / s0), s0[r] = rowmax/127
//   [NBR+NBQ, +8)   wmt: Wm = theta*W + (1-theta)*I; block 0 zeroes guards
__global__ __launch_bounds__(256) void k_prepA(
        const int* __restrict__ src, const int* __restrict__ dst,
        int* __restrict__ bcur, int2* __restrict__ pairs,
        int* __restrict__ cntA, int2* __restrict__ listA,
        const float4* __restrict__ x4,
        uint2* __restrict__ xs8, float* __restrict__ s0,
        float* __restrict__ sxs,
        const float* __restrict__ W, uint4* __restrict__ wmt,
        const float* __restrict__ lamda_p, const void* __restrict__ l_p,
        int E, int n, int NBUK, int NBR, int NBQ) {
    const int t = threadIdx.x;
    int bid = blockIdx.x;

    if (bid < NBR) {                    // ---- rank role ----
        __shared__ int2 stag[CHUNK];    // 16 KB
        __shared__ int hist[256], scn[256], lb[256], gb[256];
        hist[t] = 0;
        __syncthreads();
        int base = bid * CHUNK;
        int2 e[8];
        int bk[8], rk[8];
        #pragma unroll
        for (int i = 0; i < 8; ++i) {
            int idx = base + i * 256 + t;
            if (idx < E) {
                e[i].x = src[idx];
                e[i].y = dst[idx];
                bk[i] = e[i].y >> 8;
                rk[i] = atomicAdd(&hist[bk[i]], 1);
            } else {
                bk[i] = -1;
            }
        }
        __syncthreads();
        scn[t] = hist[t];
        __syncthreads();
        for (int k = 1; k < 256; k <<= 1) {
            int add = (t >= k) ? scn[t - k] : 0;
            __syncthreads();
            scn[t] += add;
            __syncthreads();
        }
        lb[t] = scn[t] - hist[t];
        if (t < NBUK && hist[t] > 0) gb[t] = atomicAdd(&bcur[t], hist[t]);
        else gb[t] = 0;
        __syncthreads();
        #pragma unroll
        for (int i = 0; i < 8; ++i)
            if (bk[i] >= 0) stag[lb[bk[i]] + rk[i]] = e[i];
        __syncthreads();
        int total = scn[255];
        for (int p = t; p < total; p += 256) {
            int2 pr = stag[p];
            int b = pr.y >> 8;
            int slot = gb[b] + (p - lb[b]);
            if (slot < BCAP) {
                pairs[(size_t)b * BCAP + slot] = pr;
            } else {
                int o = atomicAdd(cntA, 1);
                if (o < CAPA) listA[o] = pr;
            }
        }
        return;
    }
    bid -= NBR;

    if (bid < NBQ) {                    // ---- quant role ----
        int gid = bid * 256 + t;
        int r = gid >> 4;
        if (r >= n) return;
        int q = gid & 15;
        float4 v0 = x4[(size_t)r * 32 + q * 2];
        float4 v1 = x4[(size_t)r * 32 + q * 2 + 1];
        float f[8] = {v0.x, v0.y, v0.z, v0.w, v1.x, v1.y, v1.z, v1.w};
        float m = 0.f;
        #pragma unroll
        for (int i = 0; i < 8; ++i) m = fmaxf(m, fabsf(f[i]));
        #pragma unroll
        for (int off = 1; off < 16; off <<= 1)
            m = fmaxf(m, __shfl_xor(m, off, 16));
        float s = m * (1.f / 127.f);
        float rs = m > 0.f ? 127.f / m : 0.f;
        unsigned b[8];
        #pragma unroll
        for (int i = 0; i < 8; ++i)
            b[i] = (unsigned)(__float2int_rn(f[i] * rs) + 128);
        uint2 o;
        o.x = b[0] | (b[1] << 8) | (b[2] << 16) | (b[3] << 24);
        o.y = b[4] | (b[5] << 8) | (b[6] << 16) | (b[7] << 24);
        xs8[(size_t)r * 16 + q] = o;
        if (q == 0) s0[r] = s;
        return;
    }
    bid -= NBQ;                         // ---- wmt role (bid 0..7) ----
    if (bid == 0) {                     // zero guards (row index -1)
        if (t < 32) ((unsigned*)xs8)[(int)t - 32] = 0u;
        if (t == 32) sxs[-1] = 0.f;
    }
    int tid = bid * 256 + t;
    float lamda = *lamda_p;
    float lf = int_or_float(l_p);
    float theta = logf(lamda / lf + 1.0f);
    float omt = 1.0f - theta;
    int ct = tid >> 8, kb = (tid >> 6) & 3, kg = (tid >> 4) & 3, lc = tid & 15;
    int c = ct * 16 + lc;
    int k0 = kb * 32 + kg * 8;
    float v[8];
    #pragma unroll
    for (int j = 0; j < 8; ++j) {
        float wv = theta * W[(size_t)(k0 + j) * D + c];
        if (k0 + j == c) wv += omt;
        v[j] = wv;
    }
    uint4 o;
    o.x = pack_bf2(v[0], v[1]);
    o.y = pack_bf2(v[2], v[3]);
    o.z = pack_bf2(v[4], v[5]);
    o.w = pack_bf2(v[6], v[7]);
    wmt[tid] = o;
}

// k_prepB: one block per bucket (256 dst rows). Build padded plane rows +
// deg in LDS, consume listA (bucket-cap overflow), emit listB (deg>32),
// write planes/deg/sxs coalesced.
__global__ __launch_bounds__(256) void k_prepB(
        const int2* __restrict__ pairs, const int* __restrict__ bcur,
        const int* __restrict__ cntA, const int2* __restrict__ listA,
        int* __restrict__ deg, int* __restrict__ planes,
        float* __restrict__ sxs, const float* __restrict__ s0,
        int* __restrict__ cntB, int2* __restrict__ listB, int n) {
    __shared__ int pl[256 * P_MAX];     // 32 KB
    __shared__ int dg[256];
    const int t = threadIdx.x;
    const int b = blockIdx.x;
    #pragma unroll
    for (int i = t; i < 256 * P_MAX; i += 256) pl[i] = -1;
    dg[t] = 0;
    __syncthreads();

    int count = bcur[b];
    if (count > BCAP) count = BCAP;
    const int2* bp = pairs + (size_t)b * BCAP;
    for (int i = t; i < count; i += 256) {
        int2 pr = bp[i];
        int lr = pr.y & 255;
        int rk = atomicAdd(&dg[lr], 1);
        if (rk < P_MAX) {
            pl[lr * P_MAX + rk] = pr.x;
        } else {
            int o = atomicAdd(cntB, 1);
            if (o < OCAP) listB[o] = pr;
        }
    }
    int ca = *cntA;                     // usually 0
    if (ca > CAPA) ca = CAPA;
    for (int i = t; i < ca; i += 256) {
        int2 pr = listA[i];
        if ((pr.y >> 8) == b) {
            int lr = pr.y & 255;
            int rk = atomicAdd(&dg[lr], 1);
            if (rk < P_MAX) {
                pl[lr * P_MAX + rk] = pr.x;
            } else {
                int o = atomicAdd(cntB, 1);
                if (o < OCAP) listB[o] = pr;
            }
        }
    }
    __syncthreads();

    int r0 = b * 256;
    for (int i = t; i < 256 * P_MAX; i += 256) {
        int r = r0 + (i >> 5);
        if (r < n) planes[(size_t)r * P_MAX + (i & 31)] = pl[i];
    }
    {
        int r = r0 + t;
        if (r < n) {
            int d = dg[t];
            deg[r] = d;
            int dd = d < 1 ? 1 : d;
            sxs[r] = s0[r] * rsqrtf((float)dd);
        }
    }
}

// dequant-accumulate 8 biased ubytes: a[i] += (float)byte_i * s
__device__ __forceinline__ void accq(float* a, uint2 v, float s) {
    a[0] += (float)(v.x & 0xffu) * s;
    a[1] += (float)((v.x >> 8) & 0xffu) * s;
    a[2] += (float)((v.x >> 16) & 0xffu) * s;
    a[3] += (float)(v.x >> 24) * s;
    a[4] += (float)(v.y & 0xffu) * s;
    a[5] += (float)((v.y >> 8) & 0xffu) * s;
    a[6] += (float)((v.y >> 16) & 0xffu) * s;
    a[7] += (float)(v.y >> 24) * s;
}

// k_fused: int8 gather (row-major planes, maskless, guard row -1) + support +
// MFMA GEMM + residual-from-xs8. Block = 256 threads = 4 waves, 16 rows.
// Only the out store is nontemporal (no write-allocate; loads stay cached).
__global__ __launch_bounds__(256) void k_fused(
        const uint2* __restrict__ xs8, const float* __restrict__ sxs,
        const float* __restrict__ s0, const int* __restrict__ planes,
        const int* __restrict__ deg, const int* __restrict__ cnt,
        const int2* __restrict__ opairs, const float* __restrict__ h0,
        const float* __restrict__ alpha_p, const uint4* __restrict__ wmt,
        float* __restrict__ out, int n) {
    __shared__ uint4 sS[256];           // 16 rows x 256 B support, swizzled
    __shared__ float sX[16 * SXP];      // 16 x 128 x-residual (stride 140)
    const int t = threadIdx.x;
    const int base = blockIdx.x * 16;

    {
        const int g = t >> 4;           // row group 0..15
        const int q = t & 15;
        int r = base + g;
        int rc = r < n ? r : 0;
        int d = r < n ? deg[rc] : 0;
        int dc = d < P_MAX ? d : P_MAX;
        const char* xsb = (const char*)xs8;
        const float4* h04 = (const float4*)h0;
        float4 hb0 = h04[(size_t)rc * 32 + q * 2];
        float4 hb1 = h04[(size_t)rc * 32 + q * 2 + 1];
        uint2 own = *(const uint2*)(xsb + (size_t)rc * 128 + q * 8);
        float s0r = s0[rc];
        const int4* prow = (const int4*)(planes + (size_t)rc * P_MAX);
        float a0[8] = {}, a1[8] = {}, a2[8] = {}, a3[8] = {};
        float ssum = 0.f;
        for (int p = 0; p < dc; p += 8) {
            int4 w0 = prow[(p >> 2) + 0];       // 8 contiguous indices
            int4 w1 = prow[(p >> 2) + 1];       // (padded entries are -1)
            float c0 = sxs[w0.x], c1 = sxs[w0.y], c2 = sxs[w0.z], c3 = sxs[w0.w];
            float c4 = sxs[w1.x], c5 = sxs[w1.y], c6 = sxs[w1.z], c7 = sxs[w1.w];
            uint2 v0 = *(const uint2*)(xsb + (long)w0.x * 128 + q * 8);
            uint2 v1 = *(const uint2*)(xsb + (long)w0.y * 128 + q * 8);
            uint2 v2 = *(const uint2*)(xsb + (long)w0.z * 128 + q * 8);
            uint2 v3 = *(const uint2*)(xsb + (long)w0.w * 128 + q * 8);
            uint2 v4 = *(const uint2*)(xsb + (long)w1.x * 128 + q * 8);
            uint2 v5 = *(const uint2*)(xsb + (long)w1.y * 128 + q * 8);
            uint2 v6 = *(const uint2*)(xsb + (long)w1.z * 128 + q * 8);
            uint2 v7 = *(const uint2*)(xsb + (long)w1.w * 128 + q * 8);
            accq(a0, v0, c0);
            accq(a1, v1, c1);
            accq(a2, v2, c2);
            accq(a3, v3, c3);
            accq(a0, v4, c4);
            accq(a1, v5, c5);
            accq(a2, v6, c6);
            accq(a3, v7, c7);
            ssum += ((c0 + c1) + (c2 + c3)) + ((c4 + c5) + (c6 + c7));
        }
        if (d > P_MAX) {                // rare (deg > 32): overflow edges
            int c = *cnt;
            if (c > OCAP) c = OCAP;
            for (int i = 0; i < c; ++i) {
                int2 pr = opairs[i];
                if (pr.y == r) {
                    float cs = sxs[pr.x];
                    uint2 v = *(const uint2*)(xsb + (long)pr.x * 128 + q * 8);
                    accq(a0, v, cs);
                    ssum += cs;
                }
            }
        }
        {
            float xi[8];
            xi[0] = ((float)(own.x & 0xffu) - 128.f) * s0r;
            xi[1] = ((float)((own.x >> 8) & 0xffu) - 128.f) * s0r;
            xi[2] = ((float)((own.x >> 16) & 0xffu) - 128.f) * s0r;
            xi[3] = ((float)(own.x >> 24) - 128.f) * s0r;
            xi[4] = ((float)(own.y & 0xffu) - 128.f) * s0r;
            xi[5] = ((float)((own.y >> 8) & 0xffu) - 128.f) * s0r;
            xi[6] = ((float)((own.y >> 16) & 0xffu) - 128.f) * s0r;
            xi[7] = ((float)(own.y >> 24) - 128.f) * s0r;
            *(float4*)&sX[g * SXP + q * 8] =
                make_float4(xi[0], xi[1], xi[2], xi[3]);
            *(float4*)&sX[g * SXP + q * 8 + 4] =
                make_float4(xi[4], xi[5], xi[6], xi[7]);
        }
        float di = rsqrtf((float)(d < 1 ? 1 : d));
        float alpha = *alpha_p;
        float ca = (1.0f - alpha) * di;
        float corr = 128.f * ssum;
        float t0 = ca * (((a0[0] + a1[0]) + (a2[0] + a3[0])) - corr) + alpha * hb0.x;
        float t1 = ca * (((a0[1] + a1[1]) + (a2[1] + a3[1])) - corr) + alpha * hb0.y;
        float t2 = ca * (((a0[2] + a1[2]) + (a2[2] + a3[2])) - corr) + alpha * hb0.z;
        float t3 = ca * (((a0[3] + a1[3]) + (a2[3] + a3[3])) - corr) + alpha * hb0.w;
        float t4 = ca * (((a0[4] + a1[4]) + (a2[4] + a3[4])) - corr) + alpha * hb1.x;
        float t5 = ca * (((a0[5] + a1[5]) + (a2[5] + a3[5])) - corr) + alpha * hb1.y;
        float t6 = ca * (((a0[6] + a1[6]) + (a2[6] + a3[6])) - corr) + alpha * hb1.z;
        float t7 = ca * (((a0[7] + a1[7]) + (a2[7] + a3[7])) - corr) + alpha * hb1.w;
        uint4 o;
        o.x = pack_bf2(t0, t1);
        o.y = pack_bf2(t2, t3);
        o.z = pack_bf2(t4, t5);
        o.w = pack_bf2(t6, t7);
        sS[g * 16 + (q ^ (g & 7))] = o;
    }
    __syncthreads();

    const int lane = t & 63;
    const int wv = t >> 6;              // wave 0..3
    const int lr = lane & 15;
    const int kg = lane >> 4;

    bf16x8 a[4];
    #pragma unroll
    for (int kb = 0; kb < 4; ++kb)
        a[kb] = ((const bf16x8*)sS)[lr * 16 + ((kb * 4 + kg) ^ (lr & 7))];

    const bf16x8* wfr = (const bf16x8*)wmt;
    #pragma unroll
    for (int j = 0; j < 2; ++j) {
        int ct = wv * 2 + j;
        f32x4 acc = (f32x4){0.f, 0.f, 0.f, 0.f};
        #pragma unroll
        for (int kb = 0; kb < 4; ++kb) {
            bf16x8 b = wfr[ct * 256 + kb * 64 + lane];
            acc = __builtin_amdgcn_mfma_f32_16x16x32_bf16(a[kb], b, acc, 0, 0, 0);
        }
        int c = ct * 16 + lr;
        #pragma unroll
        for (int reg = 0; reg < 4; ++reg) {
            int tr = kg * 4 + reg;
            int rr = base + tr;
            if (rr < n) {
                size_t off = (size_t)rr * D + c;
                __builtin_nontemporal_store(acc[reg] + sX[tr * SXP + c],
                                            &out[off]);
            }
        }
    }
}

// ==================== TIER-2 (old CSR path) kernels ======================

__global__ __launch_bounds__(256) void k_deg(const int* __restrict__ dst,
                                             int* __restrict__ deg, int E) {
    int i = blockIdx.x * 256 + threadIdx.x;
    if (i < E) atomicAdd(&deg[dst[i]], 1);
}

__global__ __launch_bounds__(256) void k_dinv(int* dd, int n) {
    int i = blockIdx.x * 256 + threadIdx.x;
    if (i < n) {
        int d = dd[i];
        if (d < 1) d = 1;
        ((float*)dd)[i] = rsqrtf((float)d);
    }
}

__global__ __launch_bounds__(256) void k_scan1(const int* __restrict__ deg,
                                               int* __restrict__ bsum, int n) {
    __shared__ int red[256];
    int b = blockIdx.x, t = threadIdx.x;
    int base = b * 1024;
    int s = 0;
    #pragma unroll
    for (int i = 0; i < 4; ++i) {
        int idx = base + i * 256 + t;
        if (idx < n) s += deg[idx];
    }
    red[t] = s;
    __syncthreads();
    for (int k = 128; k > 0; k >>= 1) {
        if (t < k) red[t] += red[t + k];
        __syncthreads();
    }
    if (t == 0) bsum[b] = red[0];
}

__global__ void k_scan2(const int* __restrict__ bsum, int* __restrict__ boff,
                        int* __restrict__ offsets, int nb, int n) {
    if (threadIdx.x == 0) {
        int acc = 0;
        for (int i = 0; i < nb; ++i) { boff[i] = acc; acc += bsum[i]; }
        offsets[n] = acc;
    }
}

__global__ __launch_bounds__(256) void k_scan3(int* __restrict__ deg,
                                               const int* __restrict__ boff,
                                               int* __restrict__ offsets,
                                               int* __restrict__ cursor, int n) {
    __shared__ int ls[256];
    int b = blockIdx.x, t = threadIdx.x;
    int base = b * 1024 + t * 4;
    int v[4];
    #pragma unroll
    for (int i = 0; i < 4; ++i) v[i] = (base + i < n) ? deg[base + i] : 0;
    int mysum = v[0] + v[1] + v[2] + v[3];
    ls[t] = mysum;
    __syncthreads();
    for (int k = 1; k < 256; k <<= 1) {
        int add = (t >= k) ? ls[t - k] : 0;
        __syncthreads();
        ls[t] += add;
        __syncthreads();
    }
    int p = boff[b] + ls[t] - mysum;
    #pragma unroll
    for (int i = 0; i < 4; ++i) {
        if (base + i < n) {
            offsets[base + i] = p;
            cursor[base + i] = p;
            int d = v[i] < 1 ? 1 : v[i];
            ((float*)deg)[base + i] = rsqrtf((float)d);
        }
        p += v[i];
    }
}

__global__ __launch_bounds__(256) void k_csr(const int* __restrict__ src,
                                             const int* __restrict__ dst,
                                             int* __restrict__ cursor,
                                             int* __restrict__ csr_src, int E) {
    int i = blockIdx.x * 256 + threadIdx.x;
    if (i < E) {
        int pos = atomicAdd(&cursor[dst[i]], 1);
        csr_src[pos] = src[i];
    }
}

__global__ __launch_bounds__(256) void k_gather(const float4* __restrict__ x4,
                                                const int* __restrict__ csr_src,
                                                const int* __restrict__ offsets,
                                                const float* __restrict__ dinv,
                                                float4* __restrict__ hacc, int n) {
    int idx = blockIdx.x * 256 + threadIdx.x;
    int r = idx >> 5;
    if (r >= n) return;
    int q = idx & 31;
    int e0 = offsets[r], e1 = offsets[r + 1];
    float4 a0 = make_float4(0.f, 0.f, 0.f, 0.f);
    float4 a1 = make_float4(0.f, 0.f, 0.f, 0.f);
    float4 a2 = make_float4(0.f, 0.f, 0.f, 0.f);
    float4 a3 = make_float4(0.f, 0.f, 0.f, 0.f);
    int e = e0;
    for (; e + 4 <= e1; e += 4) {
        int s0 = csr_src[e + 0];
        int s1 = csr_src[e + 1];
        int s2 = csr_src[e + 2];
        int s3 = csr_src[e + 3];
        float c0 = dinv[s0], c1 = dinv[s1], c2 = dinv[s2], c3 = dinv[s3];
        float4 v0 = x4[(size_t)s0 * (D / 4) + q];
        float4 v1 = x4[(size_t)s1 * (D / 4) + q];
        float4 v2 = x4[(size_t)s2 * (D / 4) + q];
        float4 v3 = x4[(size_t)s3 * (D / 4) + q];
        a0.x += v0.x * c0; a0.y += v0.y * c0; a0.z += v0.z * c0; a0.w += v0.w * c0;
        a1.x += v1.x * c1; a1.y += v1.y * c1; a1.z += v1.z * c1; a1.w += v1.w * c1;
        a2.x += v2.x * c2; a2.y += v2.y * c2; a2.z += v2.z * c2; a2.w += v2.w * c2;
        a3.x += v3.x * c3; a3.y += v3.y * c3; a3.z += v3.z * c3; a3.w += v3.w * c3;
    }
    for (; e < e1; ++e) {
        int s = csr_src[e];
        float c = dinv[s];
        float4 v = x4[(size_t)s * (D / 4) + q];
        a0.x += v.x * c; a0.y += v.y * c; a0.z += v.z * c; a0.w += v.w * c;
    }
    float4 acc;
    acc.x = (a0.x + a1.x) + (a2.x + a3.x);
    acc.y = (a0.y + a1.y) + (a2.y + a3.y);
    acc.z = (a0.z + a1.z) + (a2.z + a3.z);
    acc.w = (a0.w + a1.w) + (a2.w + a3.w);
    hacc[(size_t)r * (D / 4) + q] = acc;
}

__global__ __launch_bounds__(256) void k_scatter(const float4* __restrict__ x4,
                                                 const int* __restrict__ src,
                                                 const int* __restrict__ dst,
                                                 const float* __restrict__ dinv,
                                                 float* hacc, int E) {
    int idx = blockIdx.x * 256 + threadIdx.x;
    int e = idx >> 5;
    if (e >= E) return;
    int q = idx & 31;
    int s = src[e];
    int t = dst[e];
    float sc = dinv[s];
    float4 v = x4[(size_t)s * (D / 4) + q];
    float* h = hacc + (size_t)t * D + q * 4;
    unsafeAtomicAdd(h + 0, v.x * sc);
    unsafeAtomicAdd(h + 1, v.y * sc);
    unsafeAtomicAdd(h + 2, v.z * sc);
    unsafeAtomicAdd(h + 3, v.w * sc);
}

// old VALU epilogue (fallback paths)
__global__ __launch_bounds__(256) void k_final(float* io,
                                               const float* __restrict__ dinv,
                                               const float* __restrict__ h0,
                                               const float* __restrict__ x,
                                               const float* __restrict__ W,
                                               const float* __restrict__ lamda_p,
                                               const float* __restrict__ alpha_p,
                                               const void* __restrict__ l_p,
                                               int n) {
    __shared__ float sW[D * D];
    __shared__ float sSup[32][D];
    const int t = threadIdx.x;

    {
        const float4* W4 = (const float4*)W;
        float4* sW4 = (float4*)sW;
        #pragma unroll
        for (int i = 0; i < (D * D / 4) / 256; ++i)
            sW4[i * 256 + t] = W4[i * 256 + t];
    }

    const float alpha = *alpha_p;
    const float lamda = *lamda_p;
    const float lf = int_or_float(l_p);
    const float theta = logf(lamda / lf + 1.0f);
    const float omt = 1.0f - theta;
    const float oma = 1.0f - alpha;

    const int base = blockIdx.x * 32;

    {
        const float4* hacc4 = (const float4*)io;
        const float4* h04 = (const float4*)h0;
        #pragma unroll
        for (int i = 0; i < 4; ++i) {
            int v = i * 256 + t;
            int tr = v >> 5;
            int q = v & 31;
            int r = base + tr;
            float4 sup = make_float4(0.f, 0.f, 0.f, 0.f);
            if (r < n) {
                float ca = oma * dinv[r];
                float4 a = hacc4[(size_t)r * (D / 4) + q];
                float4 b = h04[(size_t)r * (D / 4) + q];
                sup.x = ca * a.x + alpha * b.x;
                sup.y = ca * a.y + alpha * b.y;
                sup.z = ca * a.z + alpha * b.z;
                sup.w = ca * a.w + alpha * b.w;
            }
            *(float4*)&sSup[tr][q * 4] = sup;
        }
    }
    __syncthreads();

    const int cg = t & 31;
    const int rb = t >> 5;
    float acc[4][4] = {};
    const float4* sW4 = (const float4*)sW;
    #pragma unroll 4
    for (int k = 0; k < D; ++k) {
        float4 w = sW4[k * 32 + cg];
        #pragma unroll
        for (int j = 0; j < 4; ++j) {
            float s = sSup[rb * 4 + j][k];
            acc[j][0] += s * w.x;
            acc[j][1] += s * w.y;
            acc[j][2] += s * w.z;
            acc[j][3] += s * w.w;
        }
    }

    #pragma unroll
    for (int j = 0; j < 4; ++j) {
        int tr = rb * 4 + j;
        int r = base + tr;
        if (r < n) {
            float4 xi = ((const float4*)x)[(size_t)r * (D / 4) + cg];
            float4 sp = *(const float4*)&sSup[tr][cg * 4];
            float4 o;
            o.x = theta * acc[j][0] + omt * sp.x + xi.x;
            o.y = theta * acc[j][1] + omt * sp.y + xi.y;
            o.z = theta * acc[j][2] + omt * sp.z + xi.z;
            o.w = theta * acc[j][3] + omt * sp.w + xi.w;
            ((float4*)io)[(size_t)r * (D / 4) + cg] = o;
        }
    }
}

// ================================ host ===================================

extern "C" void kernel_launch(void* const* d_in, const int* in_sizes, int n_in,
                              void* d_out, int out_size, void* d_ws, size_t ws_size,
                              hipStream_t stream) {
    const float* x = (const float*)d_in[0];
    const int* esrc = (const int*)d_in[1];
    const int* edst = (const int*)d_in[2];
    const float* h0 = (const float*)d_in[3];
    const float* W = (const float*)d_in[4];
    const float* lamda_p = (const float*)d_in[5];
    const float* alpha_p = (const float*)d_in[6];
    const void* l_p = d_in[7];

    const int E = in_sizes[1];
    const int n = in_sizes[0] / D;
    const int NBUK = (n + 255) >> 8;

    char* w = (char*)d_ws;

    // ---- tier-1 layout ----
    size_t o_bc  = 0;                                            // NBUK ints (bcur)
    size_t o_ca  = ((size_t)NBUK * 4 + 15) & ~15ull;             // cntA
    size_t o_cb  = o_ca + 16;                                    // cntB
    size_t o_la  = o_cb + 16;                                    // CAPA int2
    size_t o_lb  = (o_la + (size_t)CAPA * 8 + 15) & ~15ull;      // OCAP int2
    size_t o_deg = (o_lb + (size_t)OCAP * 8 + 15) & ~15ull;      // n ints
    size_t o_x8g = (o_deg + (size_t)n * 4 + 15) & ~15ull;        // 128B guard + n*128
    size_t o_sxg = (o_x8g + 128 + (size_t)n * 128 + 15) & ~15ull;// 16B guard + n floats
    size_t o_s0  = (o_sxg + 16 + (size_t)n * 4 + 15) & ~15ull;   // n floats
    size_t o_wmt = (o_s0 + (size_t)n * 4 + 15) & ~15ull;         // 32 KB
    size_t o_pl  = (o_wmt + 32768 + 15) & ~15ull;                // n*P_MAX ints
    size_t o_pr  = (o_pl + (size_t)n * P_MAX * 4 + 15) & ~15ull; // NBUK*BCAP int2
    size_t need1 = o_pr + (size_t)NBUK * BCAP * 8;

    if (ws_size >= need1 && NBUK <= 256) {
        int* bcur = (int*)(w + o_bc);
        int* cntA = (int*)(w + o_ca);
        int* cntB = (int*)(w + o_cb);
        int2* listA = (int2*)(w + o_la);
        int2* listB = (int2*)(w + o_lb);
        int* deg = (int*)(w + o_deg);
        uint2* xs8 = (uint2*)(w + o_x8g + 128);    // row -1 = zero guard
        float* sxs = (float*)(w + o_sxg + 16);     // sxs[-1] = zero guard
        float* s0 = (float*)(w + o_s0);
        uint4* wmt = (uint4*)(w + o_wmt);
        int* planes = (int*)(w + o_pl);
        int2* pairs = (int2*)(w + o_pr);

        k_zero<<<1, 256, 0, stream>>>((int*)w, (int)(o_la / 4));

        int NBR = (E + CHUNK - 1) / CHUNK;
        int NBQ = ((size_t)n * 16 + 255) / 256;
        k_prepA<<<NBR + NBQ + 8, 256, 0, stream>>>(
            esrc, edst, bcur, pairs, cntA, listA,
            (const float4*)x, xs8, s0, sxs, W, wmt, lamda_p, l_p,
            E, n, NBUK, NBR, NBQ);
        k_prepB<<<NBUK, 256, 0, stream>>>(
            pairs, bcur, cntA, listA, deg, planes, sxs, s0, cntB, listB, n);
        k_fused<<<(n + 15) / 16, 256, 0, stream>>>(
            xs8, sxs, s0, planes, deg, cntB, listB, h0, alpha_p, wmt,
            (float*)d_out, n);
        return;
    }

    // ---- tier-2: old CSR path ----
    const int nb = (n + 1023) / 1024;
    size_t t_deg = 0;
    size_t t_off = (t_deg + (size_t)n * 4 + 15) & ~15ull;
    size_t t_cur = (t_off + (size_t)(n + 1) * 4 + 15) & ~15ull;
    size_t t_bs  = (t_cur + (size_t)n * 4 + 15) & ~15ull;
    size_t t_bo  = (t_bs + (size_t)nb * 4 + 15) & ~15ull;
    size_t t_csr = (t_bo + (size_t)nb * 4 + 15) & ~15ull;
    size_t need2 = t_csr + (size_t)E * 4;

    int* deg = (int*)(w + t_deg);
    float* dinv = (float*)(w + t_deg);

    hipMemsetAsync(deg, 0, (size_t)n * sizeof(int), stream);
    k_deg<<<(E + 255) / 256, 256, 0, stream>>>(edst, deg, E);

    if (ws_size >= need2 && nb <= 1024) {
        int* offsets = (int*)(w + t_off);
        int* cursor  = (int*)(w + t_cur);
        int* bsum    = (int*)(w + t_bs);
        int* boff    = (int*)(w + t_bo);
        int* csr_src = (int*)(w + t_csr);

        k_scan1<<<nb, 256, 0, stream>>>(deg, bsum, n);
        k_scan2<<<1, 64, 0, stream>>>(bsum, boff, offsets, nb, n);
        k_scan3<<<nb, 256, 0, stream>>>(deg, boff, offsets, cursor, n);
        k_csr<<<(E + 255) / 256, 256, 0, stream>>>(esrc, edst, cursor, csr_src, E);
        k_gather<<<((size_t)n * 32 + 255) / 256, 256, 0, stream>>>(
            (const float4*)x, csr_src, offsets, dinv, (float4*)d_out, n);
    } else {
        k_dinv<<<(n + 255) / 256, 256, 0, stream>>>(deg, n);
        hipMemsetAsync(d_out, 0, (size_t)n * D * sizeof(float), stream);
        k_scatter<<<((size_t)E * 32 + 255) / 256, 256, 0, stream>>>(
            (const float4*)x, esrc, edst, dinv, (float*)d_out, E);
    }

    k_final<<<(n + 31) / 32, 256, 0, stream>>>(
        (float*)d_out, dinv, h0, x, W, lamda_p, alpha_p, l_p, n);
}